// Round 6
// baseline (209.316 us; speedup 1.0000x reference)
//
#include <hip/hip_runtime.h>
#include <hip/hip_bf16.h>

#define T_SEQ 2048
#define BATCH 4
#define NH    16
#define DM    1024
#define HD    64

typedef __attribute__((ext_vector_type(4))) float  f32x4;
typedef __attribute__((ext_vector_type(8))) short  s16x8;
typedef __attribute__((ext_vector_type(4))) short  s16x4;
typedef __attribute__((ext_vector_type(4))) unsigned short u16x4;

__device__ __forceinline__ unsigned short f2b(float f) {
  union { float f; unsigned u; } v; v.f = f;
  unsigned u = v.u;
  unsigned r = 0x7fffu + ((u >> 16) & 1u);
  u += r;
  return (unsigned short)(u >> 16);
}

__device__ __forceinline__ f32x4 mfma16(s16x8 a, s16x8 b, f32x4 c) {
  return __builtin_amdgcn_mfma_f32_16x16x32_bf16(a, b, c, 0, 0, 0);
}

// ---------------- fused fp32 -> bf16 convert; Q-rows of w_qkv pre-scaled by 1/8 ----------------
__global__ void cvt_all(const float* __restrict__ x, const float* __restrict__ wq,
                        const float* __restrict__ wo,
                        unsigned short* __restrict__ xb, unsigned short* __restrict__ wqb,
                        unsigned short* __restrict__ wob) {
  const int N4X = (BATCH * T_SEQ * DM) / 4;
  const int N4Q = (3 * DM * DM) / 4;
  const int N4O = (DM * DM) / 4;
  const int N4QSCALED = (DM * DM) / 4;            // first 1024 rows of w_qkv = Q weights
  int i = blockIdx.x * blockDim.x + threadIdx.x;
  int stride = gridDim.x * blockDim.x;
  for (int j = i; j < N4X + N4Q + N4O; j += stride) {
    const float* src; unsigned short* dst; int k; float scale = 1.f;
    if (j < N4X) { src = x; dst = xb; k = j; }
    else if (j < N4X + N4Q) {
      k = j - N4X; src = wq; dst = wqb;
      if (k < N4QSCALED) scale = 0.125f;          // exact: pow2 scale commutes with bf16 round
    } else { k = j - N4X - N4Q; src = wo; dst = wob; }
    f32x4 v = ((const f32x4*)src)[k];
    s16x4 o;
    o.x = (short)f2b(v.x * scale); o.y = (short)f2b(v.y * scale);
    o.z = (short)f2b(v.z * scale); o.w = (short)f2b(v.w * scale);
    ((s16x4*)dst)[k] = o;
  }
}

// ---------------- GEMM: C[M,N] = A[M,K] * B[N,K]^T, global_load_lds staging ----------------
template<int OUT_F32>
__global__ __launch_bounds__(256)
void gemm_bt(const unsigned short* __restrict__ A,
             const unsigned short* __restrict__ B,
             void* __restrict__ C, int M, int N, int K) {
  __shared__ unsigned short As[128 * 32];
  __shared__ unsigned short Bs[128 * 32];
  const int tid  = threadIdx.x;
  const int lane = tid & 63;
  const int w    = tid >> 6;
  const int wr   = w >> 1, wc = w & 1;
  const int lr   = lane & 15, g = lane >> 4;

  const int gx  = gridDim.x, nwg = gx * gridDim.y;
  const int bid = blockIdx.y * gx + blockIdx.x;
  const int qq  = nwg >> 3;
  const int b2  = (bid & 7) * qq + (bid >> 3);
  const int row0 = (b2 % gx) * 128;
  const int col0 = (b2 / gx) * 128;

  const int srow = w * 16 + (lane >> 2);
  const int scol = (lane & 3) * 8;

  f32x4 acc[4][4] = {};

  for (int kt = 0; kt < K; kt += 32) {
    __syncthreads();
#pragma unroll
    for (int s = 0; s < 2; ++s) {
      const unsigned short* srcA = A + (size_t)(row0 + s * 64 + srow) * K + kt + scol;
      __builtin_amdgcn_global_load_lds((const void*)srcA, (void*)&As[(s * 64 + w * 16) * 32], 16, 0, 0);
      const unsigned short* srcB = B + (size_t)(col0 + s * 64 + srow) * K + kt + scol;
      __builtin_amdgcn_global_load_lds((const void*)srcB, (void*)&Bs[(s * 64 + w * 16) * 32], 16, 0, 0);
    }
    __syncthreads();

    s16x8 af[4], bf[4];
#pragma unroll
    for (int m = 0; m < 4; ++m)
      af[m] = *(const s16x8*)&As[(wr * 64 + m * 16 + lr) * 32 + g * 8];
#pragma unroll
    for (int n = 0; n < 4; ++n)
      bf[n] = *(const s16x8*)&Bs[(wc * 64 + n * 16 + lr) * 32 + g * 8];
#pragma unroll
    for (int m = 0; m < 4; ++m)
#pragma unroll
      for (int n = 0; n < 4; ++n)
        acc[m][n] = mfma16(af[m], bf[n], acc[m][n]);
  }

#pragma unroll
  for (int m = 0; m < 4; ++m)
#pragma unroll
    for (int n = 0; n < 4; ++n)
#pragma unroll
      for (int i = 0; i < 4; ++i) {
        int row = row0 + wr * 64 + m * 16 + g * 4 + i;
        int col = col0 + wc * 64 + n * 16 + lr;
        if (OUT_F32)
          ((float*)C)[(size_t)row * N + col] = acc[m][n][i];
        else
          ((unsigned short*)C)[(size_t)row * N + col] = f2b(acc[m][n][i]);
      }
}

// ---------------- causal flash attention, swapped QK^T ----------------
// qkv layout: [B*T, 3072]; Q pre-scaled by 1/8 via weights
// grid: 1024 1-D blocks; qt interleaved heavy/light for inter-CU balance
__global__ __launch_bounds__(512)
void attn_kernel(const unsigned short* __restrict__ qkv,
                 unsigned short* __restrict__ out) {
  __shared__ unsigned short Ks[2][64 * 64];   // [buf][key][64d], 128B rows, XOR swizzle (row&7)<<4
  __shared__ unsigned short Vt[2][64 * 72];   // [buf][d][144B], key-pairs as u32, byte swizzle
  __shared__ unsigned short Ps[8][16 * 72];   // per-wave P, [q][key], stride 72

  const int tid  = threadIdx.x;
  const int lane = tid & 63;
  const int w    = tid >> 6;
  const int lr   = lane & 15, g = lane >> 4;
  const int bid  = blockIdx.x;
  const int bh   = bid & 63;
  const int slot = bid >> 6;
  const int qt   = (slot & 1) ? (slot >> 1) : (15 - (slot >> 1));  // {15,0,14,1,...}
  const int b    = bh >> 4, h = bh & 15;
  const int q0   = qt * 128;
  const int qr   = q0 + w * 16;
  const int qq   = qr + lr;            // this lane's query row
  const size_t rb = (size_t)b * T_SEQ;

  s16x8 qf[2];
  {
    const unsigned short* qp = qkv + (rb + qq) * 3072 + h * 64;
    qf[0] = *(const s16x8*)(qp + g * 8);
    qf[1] = *(const s16x8*)(qp + 32 + g * 8);
  }

  float mI = -1e30f, lI = 0.f;
  f32x4 o[4] = {};

  const int nt   = 2 * qt + 2;
  const int qmax = qr + 15;

  const bool grpV = (tid < 256);
  const int vd0 = (tid & 7) * 8, vr0 = (tid >> 3) * 2;
  const int t2  = tid - 256;
  const int kr0 = t2 >> 3, kc0 = t2 & 7;

  s16x8 pre0, pre1;
  {
    if (grpV) {
      const unsigned short* vp = &qkv[(rb + vr0) * 3072 + 2048 + h * 64 + vd0];
      pre0 = *(const s16x8*)vp;
      pre1 = *(const s16x8*)(vp + 3072);
    } else {
      const unsigned short* kp = &qkv[(rb + kr0) * 3072 + 1024 + h * 64 + kc0 * 8];
      pre0 = *(const s16x8*)kp;
      pre1 = *(const s16x8*)(kp + 32 * 3072);
    }
  }

  for (int t = 0; t < nt; ++t) {
    const int cur = t & 1;
    // ---- commit tile t regs -> LDS[cur] (vmcnt wait for tile-t loads lands here,
    //      one full compute-phase after they were issued) ----
    if (grpV) {
#pragma unroll
      for (int jj = 0; jj < 8; ++jj) {
        int d = vd0 + jj;
        int sw = ((d ^ (d >> 3)) & 7) << 4;
        unsigned val = (unsigned)(unsigned short)pre0[jj] |
                       ((unsigned)(unsigned short)pre1[jj] << 16);
        *(unsigned*)((char*)&Vt[cur][0] + d * 144 + ((vr0 * 2) ^ sw)) = val;
      }
    } else {
      *(s16x8*)((char*)&Ks[cur][0] + kr0 * 128 + ((kc0 * 16) ^ ((kr0 & 7) << 4))) = pre0;
      int kr1 = kr0 + 32;
      *(s16x8*)((char*)&Ks[cur][0] + kr1 * 128 + ((kc0 * 16) ^ ((kr1 & 7) << 4))) = pre1;
    }
    __syncthreads();   // publishes LDS[cur]; vmcnt already 0 (tile-t loads consumed above)

    // ---- issue tile t+1 loads AFTER the barrier: in flight during compute ----
    if (t + 1 < nt) {
      const int kv0n = (t + 1) * 64;
      if (grpV) {
        const unsigned short* vp = &qkv[(rb + kv0n + vr0) * 3072 + 2048 + h * 64 + vd0];
        pre0 = *(const s16x8*)vp;
        pre1 = *(const s16x8*)(vp + 3072);
      } else {
        const unsigned short* kp = &qkv[(rb + kv0n + kr0) * 3072 + 1024 + h * 64 + kc0 * 8];
        pre0 = *(const s16x8*)kp;
        pre1 = *(const s16x8*)(kp + 32 * 3072);
      }
    }

    const int kv0 = t * 64;
    if (kv0 <= qmax) {
      // ---- S^T = K Q^T (Q pre-scaled) ----
      f32x4 s4[4];
      __builtin_amdgcn_s_setprio(1);
#pragma unroll
      for (int kc = 0; kc < 4; ++kc) {
        int row = kc * 16 + lr;
        const char* kbase = (const char*)&Ks[cur][0] + row * 128;
        int sw = (row & 7) << 4;
        s16x8 kf0 = *(const s16x8*)(kbase + ((g * 16) ^ sw));
        s16x8 kf1 = *(const s16x8*)(kbase + ((64 + g * 16) ^ sw));
        f32x4 s = {};
        s = mfma16(kf0, qf[0], s);
        s = mfma16(kf1, qf[1], s);
        s4[kc] = s;
      }
      __builtin_amdgcn_s_setprio(0);

      // ---- causal mask: only diagonal tiles (wave-uniform test) ----
      if (kv0 + 63 > qr) {
#pragma unroll
        for (int kc = 0; kc < 4; ++kc)
#pragma unroll
          for (int i = 0; i < 4; ++i) {
            int key = kv0 + kc * 16 + g * 4 + i;
            if (key > qq) s4[kc][i] = -1e30f;
          }
      }

      // ---- online softmax, in-register + 2 shuffles; defer-max (THR=8) ----
      float mx = fmaxf(fmaxf(fmaxf(s4[0][0], s4[0][1]), fmaxf(s4[0][2], s4[0][3])),
                 fmaxf(fmaxf(fmaxf(s4[1][0], s4[1][1]), fmaxf(s4[1][2], s4[1][3])),
                 fmaxf(fmaxf(fmaxf(s4[2][0], s4[2][1]), fmaxf(s4[2][2], s4[2][3])),
                       fmaxf(fmaxf(s4[3][0], s4[3][1]), fmaxf(s4[3][2], s4[3][3])))));
      mx = fmaxf(mx, __shfl_xor(mx, 16));
      mx = fmaxf(mx, __shfl_xor(mx, 32));

      const bool defer = __all(mx - mI <= 8.f);
      float alpha;
      if (defer) {
        alpha = 1.f;               // keep mI; P bounded by e^8
      } else {
        float mn = fmaxf(mI, mx);
        alpha = __expf(mI - mn);
        mI = mn;
      }
      float rs = 0.f;
#pragma unroll
      for (int kc = 0; kc < 4; ++kc)
#pragma unroll
        for (int i = 0; i < 4; ++i) {
          float p = __expf(s4[kc][i] - mI);
          s4[kc][i] = p;
          rs += p;
        }
      rs += __shfl_xor(rs, 16);
      rs += __shfl_xor(rs, 32);
      lI = lI * alpha + rs;

      // ---- P -> per-wave LDS, row-major [q][key], b64 stores ----
      {
        char* pw = (char*)&Ps[w][0] + lr * 144;
#pragma unroll
        for (int kc = 0; kc < 4; ++kc) {
          unsigned v0 = (unsigned)f2b(s4[kc][0]) | ((unsigned)f2b(s4[kc][1]) << 16);
          unsigned v1 = (unsigned)f2b(s4[kc][2]) | ((unsigned)f2b(s4[kc][3]) << 16);
          unsigned long long pv = (unsigned long long)v0 | ((unsigned long long)v1 << 32);
          *(unsigned long long*)(pw + kc * 32 + g * 8) = pv;
        }
      }

      if (!defer) {
#pragma unroll
        for (int n = 0; n < 4; ++n)
#pragma unroll
          for (int i = 0; i < 4; ++i)
            o[n][i] *= alpha;
      }

      asm volatile("s_waitcnt lgkmcnt(0)" ::: "memory");

      // ---- O^T += V^T P ----
      __builtin_amdgcn_s_setprio(1);
#pragma unroll
      for (int kk = 0; kk < 2; ++kk) {
        s16x8 pf = *(const s16x8*)((const char*)&Ps[w][0] + lr * 144 + kk * 64 + g * 16);
#pragma unroll
        for (int n = 0; n < 4; ++n) {
          int d = n * 16 + lr;
          int sw = ((d ^ (d >> 3)) & 7) << 4;
          s16x8 vf = *(const s16x8*)((const char*)&Vt[cur][0] + d * 144 + ((kk * 64 + g * 16) ^ sw));
          o[n] = mfma16(vf, pf, o[n]);
        }
      }
      __builtin_amdgcn_s_setprio(0);
    }
  }

  // ---- epilogue ----
  float rl = 1.f / lI;
#pragma unroll
  for (int n = 0; n < 4; ++n) {
    u16x4 pk;
#pragma unroll
    for (int i = 0; i < 4; ++i) pk[i] = f2b(o[n][i] * rl);
    *(u16x4*)&out[(rb + qq) * 1024 + h * 64 + n * 16 + g * 4] = pk;
  }
}

// ---------------- launcher ----------------
extern "C" void kernel_launch(void* const* d_in, const int* in_sizes, int n_in,
                              void* d_out, int out_size, void* d_ws, size_t ws_size,
                              hipStream_t stream) {
  const float* x     = (const float*)d_in[0];
  const float* w_qkv = (const float*)d_in[1];
  const float* w_out = (const float*)d_in[2];

  const size_t n_x   = (size_t)BATCH * T_SEQ * DM;
  const size_t n_wq  = (size_t)3 * DM * DM;
  const size_t n_wo  = (size_t)DM * DM;
  const size_t n_qkv = (size_t)BATCH * T_SEQ * 3 * DM;
  const size_t need  = (n_x + n_wq + n_wo + n_qkv + n_x) * 2;
  if (ws_size < need) return;

  unsigned short* xb  = (unsigned short*)d_ws;
  unsigned short* wqb = xb + n_x;
  unsigned short* wob = wqb + n_wq;
  unsigned short* qkv = wob + n_wo;
  unsigned short* att = qkv + n_qkv;

  cvt_all<<<2048, 256, 0, stream>>>(x, w_qkv, w_out, xb, wqb, wob);

  gemm_bt<0><<<dim3(64, 24), 256, 0, stream>>>(xb, wqb, qkv, BATCH * T_SEQ, 3 * DM, DM);
  attn_kernel<<<1024, 512, 0, stream>>>(qkv, att);
  gemm_bt<1><<<dim3(64, 8), 256, 0, stream>>>(att, wob, d_out, BATCH * T_SEQ, DM, DM);
}

// Round 7
// 200.226 us; speedup vs baseline: 1.0454x; 1.0454x over previous
//
#include <hip/hip_runtime.h>
#include <hip/hip_bf16.h>

#define T_SEQ 2048
#define BATCH 4
#define NH    16
#define DM    1024
#define HD    64

typedef __attribute__((ext_vector_type(4))) float  f32x4;
typedef __attribute__((ext_vector_type(8))) short  s16x8;
typedef __attribute__((ext_vector_type(4))) short  s16x4;
typedef __attribute__((ext_vector_type(4))) unsigned short u16x4;

__device__ __forceinline__ unsigned short f2b(float f) {
  union { float f; unsigned u; } v; v.f = f;
  unsigned u = v.u;
  unsigned r = 0x7fffu + ((u >> 16) & 1u);
  u += r;
  return (unsigned short)(u >> 16);
}

__device__ __forceinline__ f32x4 mfma16(s16x8 a, s16x8 b, f32x4 c) {
  return __builtin_amdgcn_mfma_f32_16x16x32_bf16(a, b, c, 0, 0, 0);
}

__device__ __forceinline__ float exp2_fast(float x) {
  float r; asm("v_exp_f32 %0, %1" : "=v"(r) : "v"(x)); return r;
}

__device__ __forceinline__ unsigned cvt_pk_bf16(float lo, float hi) {
  unsigned r; asm("v_cvt_pk_bf16_f32 %0, %1, %2" : "=v"(r) : "v"(lo), "v"(hi)); return r;
}

// ---- fused fp32 -> bf16 convert; Q-rows of w_qkv pre-scaled by 0.125*log2(e) ----
// (softmax then runs in the 2^x domain: v_exp_f32 computes 2^x natively)
__global__ void cvt_all(const float* __restrict__ x, const float* __restrict__ wq,
                        const float* __restrict__ wo,
                        unsigned short* __restrict__ xb, unsigned short* __restrict__ wqb,
                        unsigned short* __restrict__ wob) {
  const int N4X = (BATCH * T_SEQ * DM) / 4;
  const int N4Q = (3 * DM * DM) / 4;
  const int N4O = (DM * DM) / 4;
  const int N4QSCALED = (DM * DM) / 4;            // first 1024 rows of w_qkv = Q weights
  int i = blockIdx.x * blockDim.x + threadIdx.x;
  int stride = gridDim.x * blockDim.x;
  for (int j = i; j < N4X + N4Q + N4O; j += stride) {
    const float* src; unsigned short* dst; int k; float scale = 1.f;
    if (j < N4X) { src = x; dst = xb; k = j; }
    else if (j < N4X + N4Q) {
      k = j - N4X; src = wq; dst = wqb;
      if (k < N4QSCALED) scale = 0.18033688011112042f;   // (1/8)*log2(e)
    } else { k = j - N4X - N4Q; src = wo; dst = wob; }
    f32x4 v = ((const f32x4*)src)[k];
    s16x4 o;
    o.x = (short)f2b(v.x * scale); o.y = (short)f2b(v.y * scale);
    o.z = (short)f2b(v.z * scale); o.w = (short)f2b(v.w * scale);
    ((s16x4*)dst)[k] = o;
  }
}

// ---------------- GEMM: C[M,N] = A[M,K] * B[N,K]^T, global_load_lds staging ----------------
template<int OUT_F32>
__global__ __launch_bounds__(256)
void gemm_bt(const unsigned short* __restrict__ A,
             const unsigned short* __restrict__ B,
             void* __restrict__ C, int M, int N, int K) {
  __shared__ unsigned short As[128 * 32];
  __shared__ unsigned short Bs[128 * 32];
  const int tid  = threadIdx.x;
  const int lane = tid & 63;
  const int w    = tid >> 6;
  const int wr   = w >> 1, wc = w & 1;
  const int lr   = lane & 15, g = lane >> 4;

  const int gx  = gridDim.x, nwg = gx * gridDim.y;
  const int bid = blockIdx.y * gx + blockIdx.x;
  const int cpx = nwg >> 3;
  const int b2  = (bid & 7) * cpx + (bid >> 3);
  const int row0 = (b2 % gx) * 128;
  const int col0 = (b2 / gx) * 128;

  const int srow = w * 16 + (lane >> 2);
  const int scol = (lane & 3) * 8;

  f32x4 acc[4][4] = {};

  for (int kt = 0; kt < K; kt += 32) {
    __syncthreads();
#pragma unroll
    for (int s = 0; s < 2; ++s) {
      const unsigned short* srcA = A + (size_t)(row0 + s * 64 + srow) * K + kt + scol;
      __builtin_amdgcn_global_load_lds((const void*)srcA, (void*)&As[(s * 64 + w * 16) * 32], 16, 0, 0);
      const unsigned short* srcB = B + (size_t)(col0 + s * 64 + srow) * K + kt + scol;
      __builtin_amdgcn_global_load_lds((const void*)srcB, (void*)&Bs[(s * 64 + w * 16) * 32], 16, 0, 0);
    }
    __syncthreads();

    s16x8 af[4], bf[4];
#pragma unroll
    for (int m = 0; m < 4; ++m)
      af[m] = *(const s16x8*)&As[(wr * 64 + m * 16 + lr) * 32 + g * 8];
#pragma unroll
    for (int n = 0; n < 4; ++n)
      bf[n] = *(const s16x8*)&Bs[(wc * 64 + n * 16 + lr) * 32 + g * 8];
#pragma unroll
    for (int m = 0; m < 4; ++m)
#pragma unroll
      for (int n = 0; n < 4; ++n)
        acc[m][n] = mfma16(af[m], bf[n], acc[m][n]);
  }

#pragma unroll
  for (int m = 0; m < 4; ++m)
#pragma unroll
    for (int n = 0; n < 4; ++n)
#pragma unroll
      for (int i = 0; i < 4; ++i) {
        int row = row0 + wr * 64 + m * 16 + g * 4 + i;
        int col = col0 + wc * 64 + n * 16 + lr;
        if (OUT_F32)
          ((float*)C)[(size_t)row * N + col] = acc[m][n][i];
        else
          ((unsigned short*)C)[(size_t)row * N + col] = f2b(acc[m][n][i]);
      }
}

// ---------------- causal flash attention, swapped QK^T, paired q-tiles ----------------
// qkv layout: [B*T, 3072]; Q pre-scaled by 0.125*log2e via weights (2^x softmax domain)
// grid: 512 blocks; block processes q-tiles {pi, 15-pi} -> uniform 34 tile-iters/block
__global__ __launch_bounds__(512)
void attn_kernel(const unsigned short* __restrict__ qkv,
                 unsigned short* __restrict__ out) {
  __shared__ unsigned short Ks[2][64 * 64];   // [buf][key][64d], 128B rows, XOR swizzle (row&7)<<4
  __shared__ unsigned short Vt[2][64 * 72];   // [buf][d][144B], key-pairs as u32, byte swizzle
  __shared__ unsigned short Ps[8][16 * 72];   // per-wave P, [q][key], stride 72

  const int tid  = threadIdx.x;
  const int lane = tid & 63;
  const int w    = tid >> 6;
  const int lr   = lane & 15, g = lane >> 4;
  const int bid  = blockIdx.x;
  const int bh   = bid & 63;
  const int pi   = bid >> 6;          // 0..7
  const int b    = bh >> 4, h = bh & 15;
  const size_t rb = (size_t)b * T_SEQ;

  // staging roles (phase-independent): threads 0-255 stage V (row pairs), 256-511 stage K
  const bool grpV = (tid < 256);
  const int vd0 = (tid & 7) * 8, vr0 = (tid >> 3) * 2;
  const int t2  = tid - 256;
  const int kr0 = t2 >> 3, kc0 = t2 & 7;

#pragma unroll 1
  for (int ph = 0; ph < 2; ++ph) {
    const int qt = ph ? (15 - pi) : pi;
    const int q0 = qt * 128;
    const int qr = q0 + w * 16;
    const int qq = qr + lr;            // this lane's query row
    const int nt = 2 * qt + 2;
    const int qmax = qr + 15;

    s16x8 qf[2];
    {
      const unsigned short* qp = qkv + (rb + qq) * 3072 + h * 64;
      qf[0] = *(const s16x8*)(qp + g * 8);
      qf[1] = *(const s16x8*)(qp + 32 + g * 8);
    }

    float mI = -1e30f, lI = 0.f;
    f32x4 o[4] = {};

    s16x8 pre0, pre1;
    {  // prologue: issue tile 0 of this phase
      if (grpV) {
        const unsigned short* vp = &qkv[(rb + vr0) * 3072 + 2048 + h * 64 + vd0];
        pre0 = *(const s16x8*)vp;
        pre1 = *(const s16x8*)(vp + 3072);
      } else {
        const unsigned short* kp = &qkv[(rb + kr0) * 3072 + 1024 + h * 64 + kc0 * 8];
        pre0 = *(const s16x8*)kp;
        pre1 = *(const s16x8*)(kp + 32 * 3072);
      }
    }

    for (int t = 0; t < nt; ++t) {
      const int cur = t & 1;
      // ---- commit tile t regs -> LDS[cur] ----
      if (grpV) {
#pragma unroll
        for (int jj = 0; jj < 8; ++jj) {
          int d = vd0 + jj;
          int sw = ((d ^ (d >> 3)) & 7) << 4;
          unsigned val = (unsigned)(unsigned short)pre0[jj] |
                         ((unsigned)(unsigned short)pre1[jj] << 16);
          *(unsigned*)((char*)&Vt[cur][0] + d * 144 + ((vr0 * 2) ^ sw)) = val;
        }
      } else {
        *(s16x8*)((char*)&Ks[cur][0] + kr0 * 128 + ((kc0 * 16) ^ ((kr0 & 7) << 4))) = pre0;
        int kr1 = kr0 + 32;
        *(s16x8*)((char*)&Ks[cur][0] + kr1 * 128 + ((kc0 * 16) ^ ((kr1 & 7) << 4))) = pre1;
      }
      __syncthreads();

      // ---- issue tile t+1 loads (in flight during compute) ----
      if (t + 1 < nt) {
        const int kv0n = (t + 1) * 64;
        if (grpV) {
          const unsigned short* vp = &qkv[(rb + kv0n + vr0) * 3072 + 2048 + h * 64 + vd0];
          pre0 = *(const s16x8*)vp;
          pre1 = *(const s16x8*)(vp + 3072);
        } else {
          const unsigned short* kp = &qkv[(rb + kv0n + kr0) * 3072 + 1024 + h * 64 + kc0 * 8];
          pre0 = *(const s16x8*)kp;
          pre1 = *(const s16x8*)(kp + 32 * 3072);
        }
      }

      const int kv0 = t * 64;
      if (kv0 <= qmax) {
        // ---- S^T = K Q^T (log2-domain scores) ----
        f32x4 s4[4];
        __builtin_amdgcn_s_setprio(1);
#pragma unroll
        for (int kc = 0; kc < 4; ++kc) {
          int row = kc * 16 + lr;
          const char* kbase = (const char*)&Ks[cur][0] + row * 128;
          int sw = (row & 7) << 4;
          s16x8 kf0 = *(const s16x8*)(kbase + ((g * 16) ^ sw));
          s16x8 kf1 = *(const s16x8*)(kbase + ((64 + g * 16) ^ sw));
          f32x4 s = {};
          s = mfma16(kf0, qf[0], s);
          s = mfma16(kf1, qf[1], s);
          s4[kc] = s;
        }
        __builtin_amdgcn_s_setprio(0);

        // ---- causal mask: only diagonal tiles (wave-uniform test) ----
        if (kv0 + 63 > qr) {
#pragma unroll
          for (int kc = 0; kc < 4; ++kc)
#pragma unroll
            for (int i = 0; i < 4; ++i) {
              int key = kv0 + kc * 16 + g * 4 + i;
              if (key > qq) s4[kc][i] = -1e30f;
            }
        }

        // ---- online softmax (2^x domain); defer-max THR = 8*log2e ~= 11.5 ----
        float mx = fmaxf(fmaxf(fmaxf(s4[0][0], s4[0][1]), fmaxf(s4[0][2], s4[0][3])),
                   fmaxf(fmaxf(fmaxf(s4[1][0], s4[1][1]), fmaxf(s4[1][2], s4[1][3])),
                   fmaxf(fmaxf(fmaxf(s4[2][0], s4[2][1]), fmaxf(s4[2][2], s4[2][3])),
                         fmaxf(fmaxf(s4[3][0], s4[3][1]), fmaxf(s4[3][2], s4[3][3])))));
        mx = fmaxf(mx, __shfl_xor(mx, 16));
        mx = fmaxf(mx, __shfl_xor(mx, 32));

        const bool defer = __all(mx - mI <= 11.5f);
        float alpha;
        if (defer) {
          alpha = 1.f;               // keep mI; P bounded by 2^11.5
        } else {
          float mn = fmaxf(mI, mx);
          alpha = exp2_fast(mI - mn);
          mI = mn;
        }
        float rs = 0.f;
#pragma unroll
        for (int kc = 0; kc < 4; ++kc)
#pragma unroll
          for (int i = 0; i < 4; ++i) {
            float p = exp2_fast(s4[kc][i] - mI);
            s4[kc][i] = p;
            rs += p;
          }
        rs += __shfl_xor(rs, 16);
        rs += __shfl_xor(rs, 32);
        lI = lI * alpha + rs;

        // ---- P -> per-wave LDS via v_cvt_pk_bf16_f32, b64 stores ----
        {
          char* pw = (char*)&Ps[w][0] + lr * 144;
#pragma unroll
          for (int kc = 0; kc < 4; ++kc) {
            unsigned v0 = cvt_pk_bf16(s4[kc][0], s4[kc][1]);
            unsigned v1 = cvt_pk_bf16(s4[kc][2], s4[kc][3]);
            unsigned long long pv = (unsigned long long)v0 | ((unsigned long long)v1 << 32);
            *(unsigned long long*)(pw + kc * 32 + g * 8) = pv;
          }
        }

        if (!defer) {
#pragma unroll
          for (int n = 0; n < 4; ++n)
#pragma unroll
            for (int i = 0; i < 4; ++i)
              o[n][i] *= alpha;
        }

        asm volatile("s_waitcnt lgkmcnt(0)" ::: "memory");

        // ---- O^T += V^T P ----
        __builtin_amdgcn_s_setprio(1);
#pragma unroll
        for (int kk = 0; kk < 2; ++kk) {
          s16x8 pf = *(const s16x8*)((const char*)&Ps[w][0] + lr * 144 + kk * 64 + g * 16);
#pragma unroll
          for (int n = 0; n < 4; ++n) {
            int d = n * 16 + lr;
            int sw = ((d ^ (d >> 3)) & 7) << 4;
            s16x8 vf = *(const s16x8*)((const char*)&Vt[cur][0] + d * 144 + ((kk * 64 + g * 16) ^ sw));
            o[n] = mfma16(vf, pf, o[n]);
          }
        }
        __builtin_amdgcn_s_setprio(0);
      }
    }

    // ---- epilogue for this phase ----
    float rl = 1.f / lI;
#pragma unroll
    for (int n = 0; n < 4; ++n) {
      unsigned p0 = cvt_pk_bf16(o[n][0] * rl, o[n][1] * rl);
      unsigned p1 = cvt_pk_bf16(o[n][2] * rl, o[n][3] * rl);
      unsigned long long pv = (unsigned long long)p0 | ((unsigned long long)p1 << 32);
      *(unsigned long long*)&out[(rb + qq) * 1024 + h * 64 + n * 16 + g * 4] = pv;
    }
  }
}

// ---------------- launcher ----------------
extern "C" void kernel_launch(void* const* d_in, const int* in_sizes, int n_in,
                              void* d_out, int out_size, void* d_ws, size_t ws_size,
                              hipStream_t stream) {
  const float* x     = (const float*)d_in[0];
  const float* w_qkv = (const float*)d_in[1];
  const float* w_out = (const float*)d_in[2];

  const size_t n_x   = (size_t)BATCH * T_SEQ * DM;
  const size_t n_wq  = (size_t)3 * DM * DM;
  const size_t n_wo  = (size_t)DM * DM;
  const size_t n_qkv = (size_t)BATCH * T_SEQ * 3 * DM;
  const size_t need  = (n_x + n_wq + n_wo + n_qkv + n_x) * 2;
  if (ws_size < need) return;

  unsigned short* xb  = (unsigned short*)d_ws;
  unsigned short* wqb = xb + n_x;
  unsigned short* wob = wqb + n_wq;
  unsigned short* qkv = wob + n_wo;
  unsigned short* att = qkv + n_qkv;

  cvt_all<<<2048, 256, 0, stream>>>(x, w_qkv, w_out, xb, wqb, wob);

  gemm_bt<0><<<dim3(64, 24), 256, 0, stream>>>(xb, wqb, qkv, BATCH * T_SEQ, 3 * DM, DM);
  attn_kernel<<<512, 512, 0, stream>>>(qkv, att);
  gemm_bt<1><<<dim3(64, 8), 256, 0, stream>>>(att, wob, d_out, BATCH * T_SEQ, DM, DM);
}

// Round 9
// 199.306 us; speedup vs baseline: 1.0502x; 1.0046x over previous
//
#include <hip/hip_runtime.h>
#include <hip/hip_bf16.h>

#define T_SEQ 2048
#define BATCH 4
#define NH    16
#define DM    1024
#define HD    64

typedef __attribute__((ext_vector_type(4))) float  f32x4;
typedef __attribute__((ext_vector_type(8))) short  s16x8;
typedef __attribute__((ext_vector_type(4))) short  s16x4;

__device__ __forceinline__ unsigned short f2b(float f) {
  union { float f; unsigned u; } v; v.f = f;
  unsigned u = v.u;
  unsigned r = 0x7fffu + ((u >> 16) & 1u);
  u += r;
  return (unsigned short)(u >> 16);
}

__device__ __forceinline__ f32x4 mfma16(s16x8 a, s16x8 b, f32x4 c) {
  return __builtin_amdgcn_mfma_f32_16x16x32_bf16(a, b, c, 0, 0, 0);
}

__device__ __forceinline__ float exp2_fast(float x) {
  float r; asm("v_exp_f32 %0, %1" : "=v"(r) : "v"(x)); return r;
}

__device__ __forceinline__ unsigned cvt_pk_bf16(float lo, float hi) {
  unsigned r; asm("v_cvt_pk_bf16_f32 %0, %1, %2" : "=v"(r) : "v"(lo), "v"(hi)); return r;
}

#define BAR() __builtin_amdgcn_s_barrier()
#define SCB() __builtin_amdgcn_sched_barrier(0)
#define LGK(n) do { asm volatile("s_waitcnt lgkmcnt(" #n ")" ::: "memory"); SCB(); } while (0)
#define VMC(n) do { asm volatile("s_waitcnt vmcnt(" #n ")" ::: "memory"); } while (0)

// ---- fused fp32 -> bf16 convert; Q-rows of w_qkv pre-scaled by 0.125*log2(e) ----
__global__ void cvt_all(const float* __restrict__ x, const float* __restrict__ wq,
                        const float* __restrict__ wo,
                        unsigned short* __restrict__ xb, unsigned short* __restrict__ wqb,
                        unsigned short* __restrict__ wob) {
  const int N4X = (BATCH * T_SEQ * DM) / 4;
  const int N4Q = (3 * DM * DM) / 4;
  const int N4O = (DM * DM) / 4;
  const int N4QSCALED = (DM * DM) / 4;
  int i = blockIdx.x * blockDim.x + threadIdx.x;
  int stride = gridDim.x * blockDim.x;
  for (int j = i; j < N4X + N4Q + N4O; j += stride) {
    const float* src; unsigned short* dst; int k; float scale = 1.f;
    if (j < N4X) { src = x; dst = xb; k = j; }
    else if (j < N4X + N4Q) {
      k = j - N4X; src = wq; dst = wqb;
      if (k < N4QSCALED) scale = 0.18033688011112042f;   // (1/8)*log2(e)
    } else { k = j - N4X - N4Q; src = wo; dst = wob; }
    f32x4 v = ((const f32x4*)src)[k];
    s16x4 o;
    o.x = (short)f2b(v.x * scale); o.y = (short)f2b(v.y * scale);
    o.z = (short)f2b(v.z * scale); o.w = (short)f2b(v.w * scale);
    ((s16x4*)dst)[k] = o;
  }
}

// ================= 256x256 8-phase GEMM: C[M,N] = A[M,K]*B[N,K]^T, bf16 out ============
__device__ __forceinline__ void rd4(s16x8 (&d)[4], const char* base, int rbase, int cb) {
#pragma unroll
  for (int j = 0; j < 4; ++j)
    d[j] = *(const s16x8*)(base + (rbase + j * 16) * 128 + cb);
}

__device__ __forceinline__ void stage_half(const unsigned short* __restrict__ Msrc,
                                           int rt0, int kt, char* lbase, int half,
                                           int srow8, int c2src, int c2lin, int Kd) {
#pragma unroll
  for (int q = 0; q < 2; ++q) {
    int rl = half * 128 + q * 64 + srow8;
    const char* src = (const char*)(Msrc + (size_t)(rt0 + rl) * Kd + kt) + c2src;
    __builtin_amdgcn_global_load_lds((const void*)src, (void*)(lbase + rl * 128 + c2lin),
                                     16, 0, 0);
  }
}

__device__ __forceinline__ void clust(f32x4 (&acc)[8][4], const s16x8 (&a)[4],
                                      const s16x8 (&b)[4], int mb) {
  __builtin_amdgcn_s_setprio(1);
#pragma unroll
  for (int j = 0; j < 4; ++j)
#pragma unroll
    for (int n = 0; n < 4; ++n)
      acc[mb + j][n] = mfma16(a[j], b[n], acc[mb + j][n]);
  __builtin_amdgcn_s_setprio(0);
}

__global__ __launch_bounds__(512, 2)
void gemm8p(const unsigned short* __restrict__ A, const unsigned short* __restrict__ B,
            unsigned short* __restrict__ C, int M, int N, int K) {
  __shared__ char smem[131072];
  char* A0b = smem;
  char* A1b = smem + 32768;
  char* B0b = smem + 65536;
  char* B1b = smem + 98304;

  const int tid = threadIdx.x;
  const int lane = tid & 63;
  const int w = tid >> 6;
  const int wm = w >> 2, wn = w & 3;
  const int lr = lane & 15, g = lane >> 4;

  // XCD-aware bijective swizzle (grid total % 8 == 0)
  const int gx = gridDim.x, nwg = gx * gridDim.y;
  const int bid = blockIdx.y * gx + blockIdx.x;
  const int cpx = nwg >> 3;
  const int b2 = (bid & 7) * cpx + (bid >> 3);
  const int row0 = (b2 % gx) * 256;
  const int col0 = (b2 / gx) * 256;

  // staging per-thread constants
  const int srow8 = tid >> 3;                     // 0..63
  const int c2lin = (tid & 7) * 16;               // linear LDS byte col
  const int swzS = ((srow8 & 4) << 3) | ((srow8 & 8) << 1);
  const int c2src = c2lin ^ swzS;                 // pre-swizzled global byte col

  // read-side per-lane constants (swizzle collapses to lane-constant XOR)
  const int swzL = ((lr & 4) << 3) | ((lr & 8) << 1);
  const int cs0 = (g * 16) ^ swzL;                // kstep 0 byte col
  const int cs1 = 64 + cs0;                       // kstep 1
  const int rAlo = wm * 128 + lr;                 // A frag row base, m 0-3
  const int rAhi = rAlo + 64;                     // m 4-7
  const int rB = wn * 64 + lr;                    // B frag row base

  f32x4 acc[8][4] = {};
  s16x8 aP[4], aQ[4], aR[4], bP[4], bQ[4];

  const int NITER = K / 128;      // 2 K-tiles per iteration
  const int ktLast = K - 64;

  // ---- prologue: stage tile0 fully (buf0) + tile1.A0 (buf1) ----
  stage_half(A, row0, 0, A0b, 0, srow8, c2src, c2lin, K);
  stage_half(A, row0, 0, A0b, 1, srow8, c2src, c2lin, K);
  stage_half(B, col0, 0, B0b, 0, srow8, c2src, c2lin, K);
  stage_half(B, col0, 0, B0b, 1, srow8, c2src, c2lin, K);
  stage_half(A, row0, 64, A1b, 0, srow8, c2src, c2lin, K);
  VMC(2);
  BAR();
  rd4(aP, A0b, rAlo, cs0);
  rd4(bP, B0b, rB, cs0);

  for (int it = 0; it < NITER; ++it) {
    const int ktO = it * 128 + 64;
    const int kt2 = min(it * 128 + 128, ktLast);
    const int kt3 = min(it * 128 + 192, ktLast);

    // ph0: E s0 lo
    rd4(aQ, A0b, rAhi, cs0);
    stage_half(B, col0, ktO, B1b, 0, srow8, c2src, c2lin, K);
    BAR(); LGK(4);
    clust(acc, aP, bP, 0);
    BAR();
    // ph1: E s0 hi
    rd4(aP, A0b, rAlo, cs1);
    rd4(aR, A0b, rAhi, cs1);
    rd4(bQ, B0b, rB, cs1);
    stage_half(B, col0, ktO, B1b, 1, srow8, c2src, c2lin, K);
    BAR(); LGK(12);
    clust(acc, aQ, bP, 4);
    BAR();
    // ph2: E s1 lo
    stage_half(A, row0, ktO, A1b, 1, srow8, c2src, c2lin, K);
    BAR(); LGK(0);
    clust(acc, aP, bQ, 0);
    BAR();
    // ph3: E s1 hi (K-tile boundary: counted vmcnt, then O s0 reads post-barrier)
    stage_half(A, row0, kt2, A0b, 0, srow8, c2src, c2lin, K);
    VMC(2);
    BAR();
    rd4(aP, A1b, rAlo, cs0);
    rd4(bP, B1b, rB, cs0);
    clust(acc, aR, bQ, 4);
    BAR();
    // ph4: O s0 lo
    rd4(aQ, A1b, rAhi, cs0);
    stage_half(B, col0, kt2, B0b, 0, srow8, c2src, c2lin, K);
    BAR(); LGK(4);
    clust(acc, aP, bP, 0);
    BAR();
    // ph5: O s0 hi
    rd4(aP, A1b, rAlo, cs1);
    rd4(aR, A1b, rAhi, cs1);
    rd4(bQ, B1b, rB, cs1);
    stage_half(B, col0, kt2, B0b, 1, srow8, c2src, c2lin, K);
    BAR(); LGK(12);
    clust(acc, aQ, bP, 4);
    BAR();
    // ph6: O s1 lo
    stage_half(A, row0, kt2, A0b, 1, srow8, c2src, c2lin, K);
    BAR(); LGK(0);
    clust(acc, aP, bQ, 0);
    BAR();
    // ph7: O s1 hi (K-tile boundary)
    stage_half(A, row0, kt3, A1b, 0, srow8, c2src, c2lin, K);
    VMC(2);
    BAR();
    rd4(aP, A0b, rAlo, cs0);
    rd4(bP, B0b, rB, cs0);
    clust(acc, aR, bQ, 4);
    BAR();
  }

  // ---- epilogue: C bf16 ----
#pragma unroll
  for (int m = 0; m < 8; ++m)
#pragma unroll
    for (int n = 0; n < 4; ++n)
#pragma unroll
      for (int i = 0; i < 4; ++i) {
        int row = row0 + wm * 128 + m * 16 + g * 4 + i;
        int col = col0 + wn * 64 + n * 16 + lr;
        C[(size_t)row * N + col] = f2b(acc[m][n][i]);
      }
}

// ---------------- GEMM (m97 structure): C[M,N] = A[M,K] * B[N,K]^T ----------------
template<int OUT_F32>
__global__ __launch_bounds__(256)
void gemm_bt(const unsigned short* __restrict__ A,
             const unsigned short* __restrict__ B,
             void* __restrict__ C, int M, int N, int K) {
  __shared__ unsigned short As[128 * 32];
  __shared__ unsigned short Bs[128 * 32];
  const int tid  = threadIdx.x;
  const int lane = tid & 63;
  const int w    = tid >> 6;
  const int wr   = w >> 1, wc = w & 1;
  const int lr   = lane & 15, g = lane >> 4;

  const int gx  = gridDim.x, nwg = gx * gridDim.y;
  const int bid = blockIdx.y * gx + blockIdx.x;
  const int cpx = nwg >> 3;
  const int b2  = (bid & 7) * cpx + (bid >> 3);
  const int row0 = (b2 % gx) * 128;
  const int col0 = (b2 / gx) * 128;

  const int srow = w * 16 + (lane >> 2);
  const int scol = (lane & 3) * 8;

  f32x4 acc[4][4] = {};

  for (int kt = 0; kt < K; kt += 32) {
    __syncthreads();
#pragma unroll
    for (int s = 0; s < 2; ++s) {
      const unsigned short* srcA = A + (size_t)(row0 + s * 64 + srow) * K + kt + scol;
      __builtin_amdgcn_global_load_lds((const void*)srcA, (void*)&As[(s * 64 + w * 16) * 32], 16, 0, 0);
      const unsigned short* srcB = B + (size_t)(col0 + s * 64 + srow) * K + kt + scol;
      __builtin_amdgcn_global_load_lds((const void*)srcB, (void*)&Bs[(s * 64 + w * 16) * 32], 16, 0, 0);
    }
    __syncthreads();

    s16x8 af[4], bf[4];
#pragma unroll
    for (int m = 0; m < 4; ++m)
      af[m] = *(const s16x8*)&As[(wr * 64 + m * 16 + lr) * 32 + g * 8];
#pragma unroll
    for (int n = 0; n < 4; ++n)
      bf[n] = *(const s16x8*)&Bs[(wc * 64 + n * 16 + lr) * 32 + g * 8];
#pragma unroll
    for (int m = 0; m < 4; ++m)
#pragma unroll
      for (int n = 0; n < 4; ++n)
        acc[m][n] = mfma16(af[m], bf[n], acc[m][n]);
  }

#pragma unroll
  for (int m = 0; m < 4; ++m)
#pragma unroll
    for (int n = 0; n < 4; ++n)
#pragma unroll
      for (int i = 0; i < 4; ++i) {
        int row = row0 + wr * 64 + m * 16 + g * 4 + i;
        int col = col0 + wc * 64 + n * 16 + lr;
        if (OUT_F32)
          ((float*)C)[(size_t)row * N + col] = acc[m][n][i];
        else
          ((unsigned short*)C)[(size_t)row * N + col] = f2b(acc[m][n][i]);
      }
}

// ---------------- causal flash attention, swapped QK^T, paired q-tiles ----------------
__global__ __launch_bounds__(512)
void attn_kernel(const unsigned short* __restrict__ qkv,
                 unsigned short* __restrict__ out) {
  __shared__ unsigned short Ks[2][64 * 64];
  __shared__ unsigned short Vt[2][64 * 72];
  __shared__ unsigned short Ps[8][16 * 72];

  const int tid  = threadIdx.x;
  const int lane = tid & 63;
  const int w    = tid >> 6;
  const int lr   = lane & 15, g = lane >> 4;
  const int bid  = blockIdx.x;
  const int bh   = bid & 63;
  const int pi   = bid >> 6;
  const int b    = bh >> 4, h = bh & 15;
  const size_t rb = (size_t)b * T_SEQ;

  const bool grpV = (tid < 256);
  const int vd0 = (tid & 7) * 8, vr0 = (tid >> 3) * 2;
  const int t2  = tid - 256;
  const int kr0 = t2 >> 3, kc0 = t2 & 7;

#pragma unroll 1
  for (int ph = 0; ph < 2; ++ph) {
    const int qt = ph ? (15 - pi) : pi;
    const int q0 = qt * 128;
    const int qr = q0 + w * 16;
    const int qq = qr + lr;
    const int nt = 2 * qt + 2;
    const int qmax = qr + 15;

    s16x8 qf[2];
    {
      const unsigned short* qp = qkv + (rb + qq) * 3072 + h * 64;
      qf[0] = *(const s16x8*)(qp + g * 8);
      qf[1] = *(const s16x8*)(qp + 32 + g * 8);
    }

    float mI = -1e30f, lI = 0.f;
    f32x4 o[4] = {};

    s16x8 pre0, pre1;
    {
      if (grpV) {
        const unsigned short* vp = &qkv[(rb + vr0) * 3072 + 2048 + h * 64 + vd0];
        pre0 = *(const s16x8*)vp;
        pre1 = *(const s16x8*)(vp + 3072);
      } else {
        const unsigned short* kp = &qkv[(rb + kr0) * 3072 + 1024 + h * 64 + kc0 * 8];
        pre0 = *(const s16x8*)kp;
        pre1 = *(const s16x8*)(kp + 32 * 3072);
      }
    }

    for (int t = 0; t < nt; ++t) {
      const int cur = t & 1;
      if (grpV) {
#pragma unroll
        for (int jj = 0; jj < 8; ++jj) {
          int d = vd0 + jj;
          int sw = ((d ^ (d >> 3)) & 7) << 4;
          unsigned val = (unsigned)(unsigned short)pre0[jj] |
                         ((unsigned)(unsigned short)pre1[jj] << 16);
          *(unsigned*)((char*)&Vt[cur][0] + d * 144 + ((vr0 * 2) ^ sw)) = val;
        }
      } else {
        *(s16x8*)((char*)&Ks[cur][0] + kr0 * 128 + ((kc0 * 16) ^ ((kr0 & 7) << 4))) = pre0;
        int kr1 = kr0 + 32;
        *(s16x8*)((char*)&Ks[cur][0] + kr1 * 128 + ((kc0 * 16) ^ ((kr1 & 7) << 4))) = pre1;
      }
      __syncthreads();

      if (t + 1 < nt) {
        const int kv0n = (t + 1) * 64;
        if (grpV) {
          const unsigned short* vp = &qkv[(rb + kv0n + vr0) * 3072 + 2048 + h * 64 + vd0];
          pre0 = *(const s16x8*)vp;
          pre1 = *(const s16x8*)(vp + 3072);
        } else {
          const unsigned short* kp = &qkv[(rb + kv0n + kr0) * 3072 + 1024 + h * 64 + kc0 * 8];
          pre0 = *(const s16x8*)kp;
          pre1 = *(const s16x8*)(kp + 32 * 3072);
        }
      }

      const int kv0 = t * 64;
      if (kv0 <= qmax) {
        f32x4 s4[4];
        __builtin_amdgcn_s_setprio(1);
#pragma unroll
        for (int kc = 0; kc < 4; ++kc) {
          int row = kc * 16 + lr;
          const char* kbase = (const char*)&Ks[cur][0] + row * 128;
          int sw = (row & 7) << 4;
          s16x8 kf0 = *(const s16x8*)(kbase + ((g * 16) ^ sw));
          s16x8 kf1 = *(const s16x8*)(kbase + ((64 + g * 16) ^ sw));
          f32x4 s = {};
          s = mfma16(kf0, qf[0], s);
          s = mfma16(kf1, qf[1], s);
          s4[kc] = s;
        }
        __builtin_amdgcn_s_setprio(0);

        if (kv0 + 63 > qr) {
#pragma unroll
          for (int kc = 0; kc < 4; ++kc)
#pragma unroll
            for (int i = 0; i < 4; ++i) {
              int key = kv0 + kc * 16 + g * 4 + i;
              if (key > qq) s4[kc][i] = -1e30f;
            }
        }

        float mx = fmaxf(fmaxf(fmaxf(s4[0][0], s4[0][1]), fmaxf(s4[0][2], s4[0][3])),
                   fmaxf(fmaxf(fmaxf(s4[1][0], s4[1][1]), fmaxf(s4[1][2], s4[1][3])),
                   fmaxf(fmaxf(fmaxf(s4[2][0], s4[2][1]), fmaxf(s4[2][2], s4[2][3])),
                         fmaxf(fmaxf(s4[3][0], s4[3][1]), fmaxf(s4[3][2], s4[3][3])))));
        mx = fmaxf(mx, __shfl_xor(mx, 16));
        mx = fmaxf(mx, __shfl_xor(mx, 32));

        const bool defer = __all(mx - mI <= 11.5f);
        float alpha;
        if (defer) {
          alpha = 1.f;
        } else {
          float mn = fmaxf(mI, mx);
          alpha = exp2_fast(mI - mn);
          mI = mn;
        }
        float rs = 0.f;
#pragma unroll
        for (int kc = 0; kc < 4; ++kc)
#pragma unroll
          for (int i = 0; i < 4; ++i) {
            float p = exp2_fast(s4[kc][i] - mI);
            s4[kc][i] = p;
            rs += p;
          }
        rs += __shfl_xor(rs, 16);
        rs += __shfl_xor(rs, 32);
        lI = lI * alpha + rs;

        {
          char* pw = (char*)&Ps[w][0] + lr * 144;
#pragma unroll
          for (int kc = 0; kc < 4; ++kc) {
            unsigned v0 = cvt_pk_bf16(s4[kc][0], s4[kc][1]);
            unsigned v1 = cvt_pk_bf16(s4[kc][2], s4[kc][3]);
            unsigned long long pv = (unsigned long long)v0 | ((unsigned long long)v1 << 32);
            *(unsigned long long*)(pw + kc * 32 + g * 8) = pv;
          }
        }

        if (!defer) {
#pragma unroll
          for (int n = 0; n < 4; ++n)
#pragma unroll
            for (int i = 0; i < 4; ++i)
              o[n][i] *= alpha;
        }

        asm volatile("s_waitcnt lgkmcnt(0)" ::: "memory");

        __builtin_amdgcn_s_setprio(1);
#pragma unroll
        for (int kk = 0; kk < 2; ++kk) {
          s16x8 pf = *(const s16x8*)((const char*)&Ps[w][0] + lr * 144 + kk * 64 + g * 16);
#pragma unroll
          for (int n = 0; n < 4; ++n) {
            int d = n * 16 + lr;
            int sw = ((d ^ (d >> 3)) & 7) << 4;
            s16x8 vf = *(const s16x8*)((const char*)&Vt[cur][0] + d * 144 + ((kk * 64 + g * 16) ^ sw));
            o[n] = mfma16(vf, pf, o[n]);
          }
        }
        __builtin_amdgcn_s_setprio(0);
      }
    }

    float rl = 1.f / lI;
#pragma unroll
    for (int n = 0; n < 4; ++n) {
      unsigned p0 = cvt_pk_bf16(o[n][0] * rl, o[n][1] * rl);
      unsigned p1 = cvt_pk_bf16(o[n][2] * rl, o[n][3] * rl);
      unsigned long long pv = (unsigned long long)p0 | ((unsigned long long)p1 << 32);
      *(unsigned long long*)&out[(rb + qq) * 1024 + h * 64 + n * 16 + g * 4] = pv;
    }
  }
}

// ---------------- launcher ----------------
extern "C" void kernel_launch(void* const* d_in, const int* in_sizes, int n_in,
                              void* d_out, int out_size, void* d_ws, size_t ws_size,
                              hipStream_t stream) {
  const float* x     = (const float*)d_in[0];
  const float* w_qkv = (const float*)d_in[1];
  const float* w_out = (const float*)d_in[2];

  const size_t n_x   = (size_t)BATCH * T_SEQ * DM;
  const size_t n_wq  = (size_t)3 * DM * DM;
  const size_t n_wo  = (size_t)DM * DM;
  const size_t n_qkv = (size_t)BATCH * T_SEQ * 3 * DM;
  const size_t need  = (n_x + n_wq + n_wo + n_qkv + n_x) * 2;
  if (ws_size < need) return;

  unsigned short* xb  = (unsigned short*)d_ws;
  unsigned short* wqb = xb + n_x;
  unsigned short* wob = wqb + n_wq;
  unsigned short* qkv = wob + n_wo;
  unsigned short* att = qkv + n_qkv;

  cvt_all<<<2048, 256, 0, stream>>>(x, w_qkv, w_out, xb, wqb, wob);

  gemm8p<<<dim3(32, 12), 512, 0, stream>>>(xb, wqb, qkv, BATCH * T_SEQ, 3 * DM, DM);
  attn_kernel<<<512, 512, 0, stream>>>(qkv, att);
  gemm_bt<1><<<dim3(64, 8), 256, 0, stream>>>(att, wob, d_out, BATCH * T_SEQ, DM, DM);
}

// Round 10
// 190.212 us; speedup vs baseline: 1.1004x; 1.0478x over previous
//
#include <hip/hip_runtime.h>
#include <hip/hip_bf16.h>

#define T_SEQ 2048
#define BATCH 4
#define NH    16
#define DM    1024
#define HD    64

typedef __attribute__((ext_vector_type(4))) float  f32x4;
typedef __attribute__((ext_vector_type(8))) short  s16x8;
typedef __attribute__((ext_vector_type(4))) short  s16x4;

__device__ __forceinline__ unsigned short f2b(float f) {
  union { float f; unsigned u; } v; v.f = f;
  unsigned u = v.u;
  unsigned r = 0x7fffu + ((u >> 16) & 1u);
  u += r;
  return (unsigned short)(u >> 16);
}

__device__ __forceinline__ f32x4 mfma16(s16x8 a, s16x8 b, f32x4 c) {
  return __builtin_amdgcn_mfma_f32_16x16x32_bf16(a, b, c, 0, 0, 0);
}

__device__ __forceinline__ float exp2_fast(float x) {
  float r; asm("v_exp_f32 %0, %1" : "=v"(r) : "v"(x)); return r;
}

__device__ __forceinline__ unsigned cvt_pk_bf16(float lo, float hi) {
  unsigned r; asm("v_cvt_pk_bf16_f32 %0, %1, %2" : "=v"(r) : "v"(lo), "v"(hi)); return r;
}

#define BAR() __builtin_amdgcn_s_barrier()
#define SCB() __builtin_amdgcn_sched_barrier(0)
#define LGK(n) do { asm volatile("s_waitcnt lgkmcnt(" #n ")" ::: "memory"); SCB(); } while (0)
#define VMC(n) do { asm volatile("s_waitcnt vmcnt(" #n ")" ::: "memory"); } while (0)

// ---- fused fp32 -> bf16 convert; Q-rows of w_qkv pre-scaled by 0.125*log2(e) ----
__global__ void cvt_all(const float* __restrict__ x, const float* __restrict__ wq,
                        const float* __restrict__ wo,
                        unsigned short* __restrict__ xb, unsigned short* __restrict__ wqb,
                        unsigned short* __restrict__ wob) {
  const int N4X = (BATCH * T_SEQ * DM) / 4;
  const int N4Q = (3 * DM * DM) / 4;
  const int N4O = (DM * DM) / 4;
  const int N4QSCALED = (DM * DM) / 4;
  int i = blockIdx.x * blockDim.x + threadIdx.x;
  int stride = gridDim.x * blockDim.x;
  for (int j = i; j < N4X + N4Q + N4O; j += stride) {
    const float* src; unsigned short* dst; int k; float scale = 1.f;
    if (j < N4X) { src = x; dst = xb; k = j; }
    else if (j < N4X + N4Q) {
      k = j - N4X; src = wq; dst = wqb;
      if (k < N4QSCALED) scale = 0.18033688011112042f;   // (1/8)*log2(e)
    } else { k = j - N4X - N4Q; src = wo; dst = wob; }
    f32x4 v = ((const f32x4*)src)[k];
    s16x4 o;
    o.x = (short)f2b(v.x * scale); o.y = (short)f2b(v.y * scale);
    o.z = (short)f2b(v.z * scale); o.w = (short)f2b(v.w * scale);
    ((s16x4*)dst)[k] = o;
  }
}

// ======= 256x256 8-phase GEMM, depth-4-phase prefetch: C = A[M,K]*B[N,K]^T, bf16 out ======
__device__ __forceinline__ void rd4(s16x8 (&d)[4], const char* base, int rbase, int cb) {
#pragma unroll
  for (int j = 0; j < 4; ++j)
    d[j] = *(const s16x8*)(base + (rbase + j * 16) * 128 + cb);
}

__device__ __forceinline__ void stage_half(const unsigned short* __restrict__ Msrc,
                                           int rt0, int kt, char* lbase, int half,
                                           int srow8, int c2src, int c2lin, int Kd) {
#pragma unroll
  for (int q = 0; q < 2; ++q) {
    int rl = half * 128 + q * 64 + srow8;
    const char* src = (const char*)(Msrc + (size_t)(rt0 + rl) * Kd + kt) + c2src;
    __builtin_amdgcn_global_load_lds((const void*)src, (void*)(lbase + rl * 128 + c2lin),
                                     16, 0, 0);
  }
}

__device__ __forceinline__ void clust(f32x4 (&acc)[8][4], const s16x8 (&a)[4],
                                      const s16x8 (&b)[4], int mb) {
  __builtin_amdgcn_s_setprio(1);
#pragma unroll
  for (int j = 0; j < 4; ++j)
#pragma unroll
    for (int n = 0; n < 4; ++n)
      acc[mb + j][n] = mfma16(a[j], b[n], acc[mb + j][n]);
  __builtin_amdgcn_s_setprio(0);
}

__global__ __launch_bounds__(512, 2)
void gemm8p(const unsigned short* __restrict__ A, const unsigned short* __restrict__ B,
            unsigned short* __restrict__ C, int M, int N, int K) {
  __shared__ char smem[131072];
  char* A0b = smem;
  char* A1b = smem + 32768;
  char* B0b = smem + 65536;
  char* B1b = smem + 98304;

  const int tid = threadIdx.x;
  const int lane = tid & 63;
  const int w = tid >> 6;
  const int wm = w >> 2, wn = w & 3;
  const int lr = lane & 15, g = lane >> 4;

  // XCD-aware bijective swizzle (grid total % 8 == 0)
  const int gx = gridDim.x, nwg = gx * gridDim.y;
  const int bid = blockIdx.y * gx + blockIdx.x;
  const int cpx = nwg >> 3;
  const int b2 = (bid & 7) * cpx + (bid >> 3);
  const int row0 = (b2 % gx) * 256;
  const int col0 = (b2 / gx) * 256;

  // staging constants: linear LDS dest (matches HW base+lane*16), source col permuted
  // involution: LDS[row][slot] holds global slot (slot ^ (row&7)); read applies same XOR.
  const int srow8 = tid >> 3;                     // 0..63
  const int c2lin = (tid & 7) * 16;
  const int c2src = ((tid & 7) ^ (srow8 & 7)) * 16;

  // read cols: slot XOR (row&7); row&7 == lr&7 for all frag rows (row bases % 8 == 0)
  const int swz = (lr & 7) << 4;
  const int cs0 = (g * 16) ^ swz;                 // k-step 0
  const int cs1 = (64 + g * 16) ^ swz;            // k-step 1
  const int rAlo = wm * 128 + lr;
  const int rAhi = rAlo + 64;
  const int rB = wn * 64 + lr;

  f32x4 acc[8][4] = {};
  s16x8 aP[4], aQ[4], aR[4], bP[4], bQ[4];

  const int NT = K / 64;          // 16 K-tiles

  // ---- prologue: tile0 fully (buf0, 8 loads) + A(tile1) h0 (buf1, 2 loads) ----
  stage_half(A, row0, 0, A0b, 0, srow8, c2src, c2lin, K);
  stage_half(A, row0, 0, A0b, 1, srow8, c2src, c2lin, K);
  stage_half(B, col0, 0, B0b, 0, srow8, c2src, c2lin, K);
  stage_half(B, col0, 0, B0b, 1, srow8, c2src, c2lin, K);
  stage_half(A, row0, 64, A1b, 0, srow8, c2src, c2lin, K);
  VMC(2);                          // waits the 8 tile0 loads; A1h0 stays in flight
  BAR();
  rd4(aP, A0b, rAlo, cs0);
  rd4(bP, B0b, rB, cs0);

  // per-tile body: 4 phases; stages t+1 (A h1, B h0, B h1) + t+2 (A h0);
  // VMC(2) once per tile waits exactly tile t+1's 8 loads (distance 3-4 phases).
  auto body = [&](char* Ac, char* Bc, char* An, char* Bn, int t) {
    const int ktn  = min(t + 1, NT - 1) * 64;
    const int ktn2 = min(t + 2, NT - 1) * 64;
    // ph0
    rd4(aQ, Ac, rAhi, cs0);
    stage_half(A, row0, ktn, An, 1, srow8, c2src, c2lin, K);
    BAR(); LGK(4);
    clust(acc, aP, bP, 0);
    BAR();
    // ph1
    rd4(aP, Ac, rAlo, cs1);
    rd4(aR, Ac, rAhi, cs1);
    rd4(bQ, Bc, rB, cs1);
    stage_half(B, col0, ktn, Bn, 0, srow8, c2src, c2lin, K);
    BAR(); LGK(12);
    clust(acc, aQ, bP, 4);
    BAR();
    // ph2  (current-buf reads fully retired at this LGK(0) -> ph3 may overwrite Ac)
    stage_half(B, col0, ktn, Bn, 1, srow8, c2src, c2lin, K);
    BAR(); LGK(0);
    clust(acc, aP, bQ, 0);
    BAR();
    // ph3 (K-tile boundary)
    stage_half(A, row0, ktn2, Ac, 0, srow8, c2src, c2lin, K);
    VMC(2);
    BAR();
    rd4(aP, An, rAlo, cs0);
    rd4(bP, Bn, rB, cs0);
    clust(acc, aR, bQ, 4);
    BAR();
  };

#pragma unroll 1
  for (int tt = 0; tt < NT; tt += 2) {
    body(A0b, B0b, A1b, B1b, tt);
    body(A1b, B1b, A0b, B0b, tt + 1);
  }

  // ---- epilogue: C bf16 ----
#pragma unroll
  for (int m = 0; m < 8; ++m)
#pragma unroll
    for (int n = 0; n < 4; ++n)
#pragma unroll
      for (int i = 0; i < 4; ++i) {
        int row = row0 + wm * 128 + m * 16 + g * 4 + i;
        int col = col0 + wn * 64 + n * 16 + lr;
        C[(size_t)row * N + col] = f2b(acc[m][n][i]);
      }
}

// ---------------- GEMM (m97 structure): C[M,N] = A[M,K] * B[N,K]^T ----------------
template<int OUT_F32>
__global__ __launch_bounds__(256)
void gemm_bt(const unsigned short* __restrict__ A,
             const unsigned short* __restrict__ B,
             void* __restrict__ C, int M, int N, int K) {
  __shared__ unsigned short As[128 * 32];
  __shared__ unsigned short Bs[128 * 32];
  const int tid  = threadIdx.x;
  const int lane = tid & 63;
  const int w    = tid >> 6;
  const int wr   = w >> 1, wc = w & 1;
  const int lr   = lane & 15, g = lane >> 4;

  const int gx  = gridDim.x, nwg = gx * gridDim.y;
  const int bid = blockIdx.y * gx + blockIdx.x;
  const int cpx = nwg >> 3;
  const int b2  = (bid & 7) * cpx + (bid >> 3);
  const int row0 = (b2 % gx) * 128;
  const int col0 = (b2 / gx) * 128;

  const int srow = w * 16 + (lane >> 2);
  const int scol = (lane & 3) * 8;

  f32x4 acc[4][4] = {};

  for (int kt = 0; kt < K; kt += 32) {
    __syncthreads();
#pragma unroll
    for (int s = 0; s < 2; ++s) {
      const unsigned short* srcA = A + (size_t)(row0 + s * 64 + srow) * K + kt + scol;
      __builtin_amdgcn_global_load_lds((const void*)srcA, (void*)&As[(s * 64 + w * 16) * 32], 16, 0, 0);
      const unsigned short* srcB = B + (size_t)(col0 + s * 64 + srow) * K + kt + scol;
      __builtin_amdgcn_global_load_lds((const void*)srcB, (void*)&Bs[(s * 64 + w * 16) * 32], 16, 0, 0);
    }
    __syncthreads();

    s16x8 af[4], bf[4];
#pragma unroll
    for (int m = 0; m < 4; ++m)
      af[m] = *(const s16x8*)&As[(wr * 64 + m * 16 + lr) * 32 + g * 8];
#pragma unroll
    for (int n = 0; n < 4; ++n)
      bf[n] = *(const s16x8*)&Bs[(wc * 64 + n * 16 + lr) * 32 + g * 8];
#pragma unroll
    for (int m = 0; m < 4; ++m)
#pragma unroll
      for (int n = 0; n < 4; ++n)
        acc[m][n] = mfma16(af[m], bf[n], acc[m][n]);
  }

#pragma unroll
  for (int m = 0; m < 4; ++m)
#pragma unroll
    for (int n = 0; n < 4; ++n)
#pragma unroll
      for (int i = 0; i < 4; ++i) {
        int row = row0 + wr * 64 + m * 16 + g * 4 + i;
        int col = col0 + wc * 64 + n * 16 + lr;
        if (OUT_F32)
          ((float*)C)[(size_t)row * N + col] = acc[m][n][i];
        else
          ((unsigned short*)C)[(size_t)row * N + col] = f2b(acc[m][n][i]);
      }
}

// ---------------- causal flash attention, swapped QK^T, paired q-tiles ----------------
__global__ __launch_bounds__(512)
void attn_kernel(const unsigned short* __restrict__ qkv,
                 unsigned short* __restrict__ out) {
  __shared__ unsigned short Ks[2][64 * 64];
  __shared__ unsigned short Vt[2][64 * 72];
  __shared__ unsigned short Ps[8][16 * 72];

  const int tid  = threadIdx.x;
  const int lane = tid & 63;
  const int w    = tid >> 6;
  const int lr   = lane & 15, g = lane >> 4;
  const int bid  = blockIdx.x;
  const int bh   = bid & 63;
  const int pi   = bid >> 6;
  const int b    = bh >> 4, h = bh & 15;
  const size_t rb = (size_t)b * T_SEQ;

  const bool grpV = (tid < 256);
  const int vd0 = (tid & 7) * 8, vr0 = (tid >> 3) * 2;
  const int t2  = tid - 256;
  const int kr0 = t2 >> 3, kc0 = t2 & 7;

#pragma unroll 1
  for (int ph = 0; ph < 2; ++ph) {
    const int qt = ph ? (15 - pi) : pi;
    const int q0 = qt * 128;
    const int qr = q0 + w * 16;
    const int qq = qr + lr;
    const int nt = 2 * qt + 2;
    const int qmax = qr + 15;

    s16x8 qf[2];
    {
      const unsigned short* qp = qkv + (rb + qq) * 3072 + h * 64;
      qf[0] = *(const s16x8*)(qp + g * 8);
      qf[1] = *(const s16x8*)(qp + 32 + g * 8);
    }

    float mI = -1e30f, lI = 0.f;
    f32x4 o[4] = {};

    s16x8 pre0, pre1;
    {
      if (grpV) {
        const unsigned short* vp = &qkv[(rb + vr0) * 3072 + 2048 + h * 64 + vd0];
        pre0 = *(const s16x8*)vp;
        pre1 = *(const s16x8*)(vp + 3072);
      } else {
        const unsigned short* kp = &qkv[(rb + kr0) * 3072 + 1024 + h * 64 + kc0 * 8];
        pre0 = *(const s16x8*)kp;
        pre1 = *(const s16x8*)(kp + 32 * 3072);
      }
    }

    for (int t = 0; t < nt; ++t) {
      const int cur = t & 1;
      if (grpV) {
#pragma unroll
        for (int jj = 0; jj < 8; ++jj) {
          int d = vd0 + jj;
          int sw = ((d ^ (d >> 3)) & 7) << 4;
          unsigned val = (unsigned)(unsigned short)pre0[jj] |
                         ((unsigned)(unsigned short)pre1[jj] << 16);
          *(unsigned*)((char*)&Vt[cur][0] + d * 144 + ((vr0 * 2) ^ sw)) = val;
        }
      } else {
        *(s16x8*)((char*)&Ks[cur][0] + kr0 * 128 + ((kc0 * 16) ^ ((kr0 & 7) << 4))) = pre0;
        int kr1 = kr0 + 32;
        *(s16x8*)((char*)&Ks[cur][0] + kr1 * 128 + ((kc0 * 16) ^ ((kr1 & 7) << 4))) = pre1;
      }
      __syncthreads();

      if (t + 1 < nt) {
        const int kv0n = (t + 1) * 64;
        if (grpV) {
          const unsigned short* vp = &qkv[(rb + kv0n + vr0) * 3072 + 2048 + h * 64 + vd0];
          pre0 = *(const s16x8*)vp;
          pre1 = *(const s16x8*)(vp + 3072);
        } else {
          const unsigned short* kp = &qkv[(rb + kv0n + kr0) * 3072 + 1024 + h * 64 + kc0 * 8];
          pre0 = *(const s16x8*)kp;
          pre1 = *(const s16x8*)(kp + 32 * 3072);
        }
      }

      const int kv0 = t * 64;
      if (kv0 <= qmax) {
        f32x4 s4[4];
        __builtin_amdgcn_s_setprio(1);
#pragma unroll
        for (int kc = 0; kc < 4; ++kc) {
          int row = kc * 16 + lr;
          const char* kbase = (const char*)&Ks[cur][0] + row * 128;
          int sw = (row & 7) << 4;
          s16x8 kf0 = *(const s16x8*)(kbase + ((g * 16) ^ sw));
          s16x8 kf1 = *(const s16x8*)(kbase + ((64 + g * 16) ^ sw));
          f32x4 s = {};
          s = mfma16(kf0, qf[0], s);
          s = mfma16(kf1, qf[1], s);
          s4[kc] = s;
        }
        __builtin_amdgcn_s_setprio(0);

        if (kv0 + 63 > qr) {
#pragma unroll
          for (int kc = 0; kc < 4; ++kc)
#pragma unroll
            for (int i = 0; i < 4; ++i) {
              int key = kv0 + kc * 16 + g * 4 + i;
              if (key > qq) s4[kc][i] = -1e30f;
            }
        }

        float mx = fmaxf(fmaxf(fmaxf(s4[0][0], s4[0][1]), fmaxf(s4[0][2], s4[0][3])),
                   fmaxf(fmaxf(fmaxf(s4[1][0], s4[1][1]), fmaxf(s4[1][2], s4[1][3])),
                   fmaxf(fmaxf(fmaxf(s4[2][0], s4[2][1]), fmaxf(s4[2][2], s4[2][3])),
                         fmaxf(fmaxf(s4[3][0], s4[3][1]), fmaxf(s4[3][2], s4[3][3])))));
        mx = fmaxf(mx, __shfl_xor(mx, 16));
        mx = fmaxf(mx, __shfl_xor(mx, 32));

        const bool defer = __all(mx - mI <= 11.5f);
        float alpha;
        if (defer) {
          alpha = 1.f;
        } else {
          float mn = fmaxf(mI, mx);
          alpha = exp2_fast(mI - mn);
          mI = mn;
        }
        float rs = 0.f;
#pragma unroll
        for (int kc = 0; kc < 4; ++kc)
#pragma unroll
          for (int i = 0; i < 4; ++i) {
            float p = exp2_fast(s4[kc][i] - mI);
            s4[kc][i] = p;
            rs += p;
          }
        rs += __shfl_xor(rs, 16);
        rs += __shfl_xor(rs, 32);
        lI = lI * alpha + rs;

        {
          char* pw = (char*)&Ps[w][0] + lr * 144;
#pragma unroll
          for (int kc = 0; kc < 4; ++kc) {
            unsigned v0 = cvt_pk_bf16(s4[kc][0], s4[kc][1]);
            unsigned v1 = cvt_pk_bf16(s4[kc][2], s4[kc][3]);
            unsigned long long pv = (unsigned long long)v0 | ((unsigned long long)v1 << 32);
            *(unsigned long long*)(pw + kc * 32 + g * 8) = pv;
          }
        }

        if (!defer) {
#pragma unroll
          for (int n = 0; n < 4; ++n)
#pragma unroll
            for (int i = 0; i < 4; ++i)
              o[n][i] *= alpha;
        }

        asm volatile("s_waitcnt lgkmcnt(0)" ::: "memory");

        __builtin_amdgcn_s_setprio(1);
#pragma unroll
        for (int kk = 0; kk < 2; ++kk) {
          s16x8 pf = *(const s16x8*)((const char*)&Ps[w][0] + lr * 144 + kk * 64 + g * 16);
#pragma unroll
          for (int n = 0; n < 4; ++n) {
            int d = n * 16 + lr;
            int sw = ((d ^ (d >> 3)) & 7) << 4;
            s16x8 vf = *(const s16x8*)((const char*)&Vt[cur][0] + d * 144 + ((kk * 64 + g * 16) ^ sw));
            o[n] = mfma16(vf, pf, o[n]);
          }
        }
        __builtin_amdgcn_s_setprio(0);
      }
    }

    float rl = 1.f / lI;
#pragma unroll
    for (int n = 0; n < 4; ++n) {
      unsigned p0 = cvt_pk_bf16(o[n][0] * rl, o[n][1] * rl);
      unsigned p1 = cvt_pk_bf16(o[n][2] * rl, o[n][3] * rl);
      unsigned long long pv = (unsigned long long)p0 | ((unsigned long long)p1 << 32);
      *(unsigned long long*)&out[(rb + qq) * 1024 + h * 64 + n * 16 + g * 4] = pv;
    }
  }
}

// ---------------- launcher ----------------
extern "C" void kernel_launch(void* const* d_in, const int* in_sizes, int n_in,
                              void* d_out, int out_size, void* d_ws, size_t ws_size,
                              hipStream_t stream) {
  const float* x     = (const float*)d_in[0];
  const float* w_qkv = (const float*)d_in[1];
  const float* w_out = (const float*)d_in[2];

  const size_t n_x   = (size_t)BATCH * T_SEQ * DM;
  const size_t n_wq  = (size_t)3 * DM * DM;
  const size_t n_wo  = (size_t)DM * DM;
  const size_t n_qkv = (size_t)BATCH * T_SEQ * 3 * DM;
  const size_t need  = (n_x + n_wq + n_wo + n_qkv + n_x) * 2;
  if (ws_size < need) return;

  unsigned short* xb  = (unsigned short*)d_ws;
  unsigned short* wqb = xb + n_x;
  unsigned short* wob = wqb + n_wq;
  unsigned short* qkv = wob + n_wo;
  unsigned short* att = qkv + n_qkv;

  cvt_all<<<2048, 256, 0, stream>>>(x, w_qkv, w_out, xb, wqb, wob);

  gemm8p<<<dim3(32, 12), 512, 0, stream>>>(xb, wqb, qkv, BATCH * T_SEQ, 3 * DM, DM);
  attn_kernel<<<512, 512, 0, stream>>>(qkv, att);
  gemm_bt<1><<<dim3(64, 8), 256, 0, stream>>>(att, wob, d_out, BATCH * T_SEQ, DM, DM);
}